// Round 1
// baseline (664.379 us; speedup 1.0000x reference)
//
#include <hip/hip_runtime.h>

// LatticeSuperpixel: B=8, C=20, H=W=512, 32x32 seeds, 16x16 cells, 4 levels.
#define NB 8
#define NC 20
#define NH 512
#define NW 512
#define NS 1024           // 32*32 seeds
#define SEEDS_ELEMS (NB * NS * NC)   // 163840
#define DENOM_ELEMS (NB * NS)        // 8192

__device__ __forceinline__ int clampi(int v, int lo, int hi) {
    return v < lo ? lo : (v > hi ? hi : v);
}

// ---------------------------------------------------------------------------
// Kernel 1: seed init = mean over each 16x16 patch, per channel.
// grid (1024 cells, 8 batches), block 256 (one thread per pixel of the patch).
// ---------------------------------------------------------------------------
__global__ __launch_bounds__(256) void k_seed_init(const float* __restrict__ x,
                                                   float* __restrict__ seeds) {
    const int t = threadIdx.x;
    const int cell = blockIdx.x;
    const int b = blockIdx.y;
    const int cy = cell >> 5, cx = cell & 31;
    const int py = (cy << 4) + (t >> 4);
    const int px = (cx << 4) + (t & 15);

    const float* xp = x + (size_t)b * (NC * NH * NW) + (size_t)py * NW + px;
    float xv[NC];
#pragma unroll
    for (int c = 0; c < NC; ++c) xv[c] = xp[(size_t)c * (NH * NW)];

    // butterfly reduce each channel across the 64-lane wave
#pragma unroll
    for (int c = 0; c < NC; ++c) {
        float v = xv[c];
#pragma unroll
        for (int off = 32; off >= 1; off >>= 1) v += __shfl_xor(v, off, 64);
        xv[c] = v;
    }

    __shared__ float part[4][NC];
    const int lane = t & 63, wv = t >> 6;
    if (lane == 0) {
#pragma unroll
        for (int c = 0; c < NC; ++c) part[wv][c] = xv[c];
    }
    __syncthreads();
    if (t < NC) {
        float s = part[0][t] + part[1][t] + part[2][t] + part[3][t];
        seeds[((size_t)(b << 10) + cell) * NC + t] = s * (1.0f / 256.0f);
    }
}

// ---------------------------------------------------------------------------
// Kernel 2: one assignment iteration with seed-update accumulation.
// Per block (= one cell): compute q for 256 pixels against the 9 clipped
// neighbor seeds, then reduce per-cell partial numer[9][20] / denom[9] and
// atomically add into global accumulators.
// ---------------------------------------------------------------------------
__global__ __launch_bounds__(256) void k_iter(const float* __restrict__ x,
                                              const float* __restrict__ seeds,
                                              float* __restrict__ numer,
                                              float* __restrict__ denom) {
    __shared__ float s_lds[9][NC];
    __shared__ float s_sn[9];
    __shared__ __align__(16) float xs[256][NC];   // [pixel][channel]
    __shared__ float qs[9][257];                  // padded stride
    __shared__ float red[216][4];

    const int t = threadIdx.x;
    const int cell = blockIdx.x;
    const int b = blockIdx.y;
    const int cy = cell >> 5, cx = cell & 31;

    const int dyo[9] = {-1, -1, -1, 0, 0, 0, 1, 1, 1};
    const int dxo[9] = {-1, 0, 1, -1, 0, 1, -1, 0, 1};

    // ---- load this pixel's channels (registers + LDS stage) ----
    const int py = (cy << 4) + (t >> 4);
    const int px = (cx << 4) + (t & 15);
    const float* xp = x + (size_t)b * (NC * NH * NW) + (size_t)py * NW + px;
    float xv[NC];
#pragma unroll
    for (int c = 0; c < NC; ++c) {
        xv[c] = xp[(size_t)c * (NH * NW)];
        xs[t][c] = xv[c];
    }

    // ---- load 9 neighbor seeds into LDS ----
    if (t < 180) {
        const int o = t / 20, c = t - o * 20;
        const int ny = clampi(cy + dyo[o], 0, 31);
        const int nx = clampi(cx + dxo[o], 0, 31);
        s_lds[o][c] = seeds[((size_t)(b << 10) + (ny << 5) + nx) * NC + c];
    }
    __syncthreads();
    if (t < 9) {
        float s = 0.f;
#pragma unroll
        for (int c = 0; c < NC; ++c) s += s_lds[t][c] * s_lds[t][c];
        s_sn[t] = s;
    }
    __syncthreads();

    // ---- shifted distances + softmax (||x||^2 cancels in softmax) ----
    float d[9];
#pragma unroll
    for (int o = 0; o < 9; ++o) {
        float ip = 0.f;
#pragma unroll
        for (int c = 0; c < NC; ++c) ip += xv[c] * s_lds[o][c];
        d[o] = s_sn[o] - 2.0f * ip;
    }
    float m = d[0];
#pragma unroll
    for (int o = 1; o < 9; ++o) m = fminf(m, d[o]);
    float w[9];
    float wsum = 0.f;
#pragma unroll
    for (int o = 0; o < 9; ++o) {
        w[o] = __expf(m - d[o]);
        wsum += w[o];
    }
    const float inv = 1.0f / wsum;
#pragma unroll
    for (int o = 0; o < 9; ++o) qs[o][t] = w[o] * inv;
    __syncthreads();

    // ---- per-cell reduction: numer[9][20] (as 5 float4) + denom[9] ----
    // 216 workers: (o, pixel-quarter pg, channel-group cg); cg==5 -> denom.
    if (t < 216) {
        const int o = t / 24, r = t - o * 24;
        const int pg = r / 6, cg = r - pg * 6;
        const int base = pg << 6;
        if (cg < 5) {
            float4 acc = make_float4(0.f, 0.f, 0.f, 0.f);
#pragma unroll 8
            for (int i = 0; i < 64; ++i) {
                const int p = base + i;
                const float qv = qs[o][p];
                const float4 xq = *reinterpret_cast<const float4*>(&xs[p][cg << 2]);
                acc.x += qv * xq.x;
                acc.y += qv * xq.y;
                acc.z += qv * xq.z;
                acc.w += qv * xq.w;
            }
            red[t][0] = acc.x; red[t][1] = acc.y; red[t][2] = acc.z; red[t][3] = acc.w;
        } else {
            float a = 0.f;
#pragma unroll 8
            for (int i = 0; i < 64; ++i) a += qs[o][base + i];
            red[t][0] = a;
        }
    }
    __syncthreads();

    // ---- combine the 4 pixel-quarters, atomically add to global ----
    if (t < 54) {
        const int o = t / 6, cg = t - o * 6;
        const int ny = clampi(cy + dyo[o], 0, 31);
        const int nx = clampi(cx + dxo[o], 0, 31);
        const size_t sidx = (size_t)(b << 10) + (ny << 5) + nx;
        const int rb = o * 24 + cg;
        if (cg < 5) {
#pragma unroll
            for (int k = 0; k < 4; ++k) {
                const float v = red[rb][k] + red[rb + 6][k] + red[rb + 12][k] + red[rb + 18][k];
                atomicAdd(&numer[sidx * NC + (cg << 2) + k], v);
            }
        } else {
            const float v = red[rb][0] + red[rb + 6][0] + red[rb + 12][0] + red[rb + 18][0];
            atomicAdd(&denom[sidx], v);
        }
    }
}

// ---------------------------------------------------------------------------
// Kernel 3: seeds = numer / (denom + eps)
// ---------------------------------------------------------------------------
__global__ __launch_bounds__(256) void k_div(float* __restrict__ seeds,
                                             const float* __restrict__ numer,
                                             const float* __restrict__ denom) {
    const int i = blockIdx.x * 256 + threadIdx.x;  // < 163840
    seeds[i] = numer[i] / (denom[i / NC] + 1e-8f);
}

// ---------------------------------------------------------------------------
// Kernel 4: final assignment pass -> write Q (B, 9, H, W)
// ---------------------------------------------------------------------------
__global__ __launch_bounds__(256) void k_final(const float* __restrict__ x,
                                               const float* __restrict__ seeds,
                                               float* __restrict__ out) {
    __shared__ float s_lds[9][NC];
    __shared__ float s_sn[9];

    const int t = threadIdx.x;
    const int cell = blockIdx.x;
    const int b = blockIdx.y;
    const int cy = cell >> 5, cx = cell & 31;

    const int dyo[9] = {-1, -1, -1, 0, 0, 0, 1, 1, 1};
    const int dxo[9] = {-1, 0, 1, -1, 0, 1, -1, 0, 1};

    const int py = (cy << 4) + (t >> 4);
    const int px = (cx << 4) + (t & 15);
    const float* xp = x + (size_t)b * (NC * NH * NW) + (size_t)py * NW + px;
    float xv[NC];
#pragma unroll
    for (int c = 0; c < NC; ++c) xv[c] = xp[(size_t)c * (NH * NW)];

    if (t < 180) {
        const int o = t / 20, c = t - o * 20;
        const int ny = clampi(cy + dyo[o], 0, 31);
        const int nx = clampi(cx + dxo[o], 0, 31);
        s_lds[o][c] = seeds[((size_t)(b << 10) + (ny << 5) + nx) * NC + c];
    }
    __syncthreads();
    if (t < 9) {
        float s = 0.f;
#pragma unroll
        for (int c = 0; c < NC; ++c) s += s_lds[t][c] * s_lds[t][c];
        s_sn[t] = s;
    }
    __syncthreads();

    float d[9];
#pragma unroll
    for (int o = 0; o < 9; ++o) {
        float ip = 0.f;
#pragma unroll
        for (int c = 0; c < NC; ++c) ip += xv[c] * s_lds[o][c];
        d[o] = s_sn[o] - 2.0f * ip;
    }
    float m = d[0];
#pragma unroll
    for (int o = 1; o < 9; ++o) m = fminf(m, d[o]);
    float w[9];
    float wsum = 0.f;
#pragma unroll
    for (int o = 0; o < 9; ++o) {
        w[o] = __expf(m - d[o]);
        wsum += w[o];
    }
    const float inv = 1.0f / wsum;
#pragma unroll
    for (int o = 0; o < 9; ++o) {
        out[(((size_t)b * 9 + o) * NH + py) * NW + px] = w[o] * inv;
    }
}

// ---------------------------------------------------------------------------
extern "C" void kernel_launch(void* const* d_in, const int* in_sizes, int n_in,
                              void* d_out, int out_size, void* d_ws, size_t ws_size,
                              hipStream_t stream) {
    const float* x = (const float*)d_in[0];
    float* out = (float*)d_out;

    float* seeds = (float*)d_ws;                 // 163840 floats
    float* numer = seeds + SEEDS_ELEMS;          // 163840 floats
    float* denom = numer + SEEDS_ELEMS;          // 8192 floats

    const dim3 grid(NS, NB);  // 1024 cells x 8 batches
    k_seed_init<<<grid, 256, 0, stream>>>(x, seeds);

    for (int it = 0; it < 3; ++it) {
        hipMemsetAsync(numer, 0, (SEEDS_ELEMS + DENOM_ELEMS) * sizeof(float), stream);
        k_iter<<<grid, 256, 0, stream>>>(x, seeds, numer, denom);
        k_div<<<SEEDS_ELEMS / 256, 256, 0, stream>>>(seeds, numer, denom);
    }
    k_final<<<grid, 256, 0, stream>>>(x, seeds, out);
}